// Round 8
// baseline (57.823 us; speedup 1.0000x reference)
//
#include <hip/hip_runtime.h>
#include <stdint.h>

typedef unsigned int u32;
typedef unsigned long long u64;

#define FACTOR  6.26f
#define D       2048
#define TPB     256
#define WPB     4        // one row per wave
#define CAP     256      // per-side candidate list capacity (mean 137, sd 11.3)
#define TH      1.5f
#define TH_BITS 0x3FC00000u

// Seeds for the 32nd-largest tail value of 2048 N(0,1): concentrated at 2.15 +/- 0.07.
#define SEED_LO (((u64)0x3FE66666u) << 32)   // 1.80f
#define SEED_HI (((u64)0x402147AEu) << 32)   // 2.52f

__device__ __forceinline__ float wsum_f(float v) {
#pragma unroll
    for (int d = 1; d < 64; d <<= 1) v += __shfl_xor(v, d, 64);
    return v;
}
__device__ __forceinline__ u32 wsum_u(u32 v) {
#pragma unroll
    for (int d = 1; d < 64; d <<= 1) v += __shfl_xor(v, d, 64);
    return v;
}
__device__ __forceinline__ float valof(u64 k) { return __uint_as_float((u32)(k >> 32)); }

__device__ __forceinline__ int cnt4(u64 k0, u64 k1, u64 k2, u64 k3, u64 mid) {
    return __popcll(__ballot(k0 >= mid)) + __popcll(__ballot(k1 >= mid))
         + __popcll(__ballot(k2 >= mid)) + __popcll(__ballot(k3 >= mid));
}

// Cold exact fallback (prob ~1e-19/row for this data): full-row key bisect with
// global re-reads + atomicAdd scatter (handles P/N overlap possible only here).
// Called AFTER zeros are stored and drained.
__device__ __attribute__((noinline))
void slow_side(const float4* __restrict__ xr, float* __restrict__ outrow,
               int lane, int neg, float sum) {
    u64 lo = 0ull, hi = ((u64)0x7F800001u) << 32;
    while (hi - lo > 1ull) {
        u64 mid = lo + ((hi - lo) >> 1);
        u32 cl = 0;
#pragma unroll 1
        for (int q = 0; q < 8; ++q) {
            float4 f = xr[q * 64 + lane];
            float vv[4] = {f.x, f.y, f.z, f.w};
#pragma unroll
            for (int c = 0; c < 4; ++c) {
                float v = neg ? -vv[c] : vv[c];
                float pv = v > 0.f ? v : 0.f;
                int idx = q * 256 + lane * 4 + c;
                u64 k = ((u64)__float_as_uint(pv) << 32) | (u64)(u32)(2047 - idx);
                cl += (k >= mid) ? 1u : 0u;
            }
        }
        u32 c = wsum_u(cl);
        if (c >= 32u) { lo = mid; if (c == 32u) break; } else hi = mid;
    }
    float ts = 0.f;
#pragma unroll 1
    for (int q = 0; q < 8; ++q) {
        float4 f = xr[q * 64 + lane];
        float vv[4] = {f.x, f.y, f.z, f.w};
#pragma unroll
        for (int c = 0; c < 4; ++c) {
            float v = neg ? -vv[c] : vv[c];
            float pv = v > 0.f ? v : 0.f;
            int idx = q * 256 + lane * 4 + c;
            u64 k = ((u64)__float_as_uint(pv) << 32) | (u64)(u32)(2047 - idx);
            if (k >= lo) ts += pv;
        }
    }
    ts = wsum_f(ts);
    float tmp = FACTOR * (sum - ts);
    float sgn = neg ? -1.f : 1.f;
#pragma unroll 1
    for (int q = 0; q < 8; ++q) {
        float4 f = xr[q * 64 + lane];
        float vv[4] = {f.x, f.y, f.z, f.w};
#pragma unroll
        for (int c = 0; c < 4; ++c) {
            float v = neg ? -vv[c] : vv[c];
            float pv = v > 0.f ? v : 0.f;
            int idx = q * 256 + lane * 4 + c;
            u64 k = ((u64)__float_as_uint(pv) << 32) | (u64)(u32)(2047 - idx);
            if (k >= lo) atomicAdd(&outrow[idx], sgn * (pv + tmp));
        }
    }
}

__global__ void __launch_bounds__(TPB, 8)
kcomp_kernel(const float* __restrict__ x, float* __restrict__ out) {
    __shared__ u64 s_list[WPB][2][CAP];   // 16 KiB/block, per-wave private

    const int t    = threadIdx.x;
    const int lane = t & 63;
    const int wave = t >> 6;
    const size_t rbase = (size_t)(blockIdx.x * WPB + wave) * D;

    const float4* xr     = reinterpret_cast<const float4*>(x + rbase);
    float4*       out4   = reinterpret_cast<float4*>(out + rbase);
    float*        outrow = out + rbase;

    // ---- pass 1: load row to regs; plain sum + abs-sum (abs = free input
    // modifier) + candidate counts. sumP = (sa+s)/2, sumN = (sa-s)/2.
    float rv[32];
    float s = 0.f, sa = 0.f;
    u32 cP = 0, cN = 0;
#pragma unroll
    for (int q = 0; q < 8; ++q) {
        float4 f = xr[q * 64 + lane];
        rv[q*4+0] = f.x; rv[q*4+1] = f.y; rv[q*4+2] = f.z; rv[q*4+3] = f.w;
#pragma unroll
        for (int c = 0; c < 4; ++c) {
            float v = rv[q*4+c];
            s  += v;
            sa += __builtin_fabsf(v);
            cP += v > TH  ? 1u : 0u;
            cN += v < -TH ? 1u : 0u;
        }
    }

    // ---- packed prefix scan for compaction offsets
    u32 packed = cP | (cN << 16);
    u32 inc = packed;
#pragma unroll
    for (int d = 1; d < 64; d <<= 1) {
        u32 n = __shfl_up(inc, (unsigned)d, 64);
        if (lane >= d) inc += n;
    }
    u32 tot  = __shfl(inc, 63, 64);
    u32 exc  = inc - packed;
    u32 totP = tot & 0xffffu, totN = tot >> 16;
    u32 offP = exc & 0xffffu, offN = exc >> 16;
    float sw  = wsum_f(s);
    float saw = wsum_f(sa);
    float sumP = 0.5f * (saw + sw);
    float sumN = 0.5f * (saw - sw);

    const bool fastP = (totP >= 32u && totP <= CAP);
    const bool fastN = (totN >= 32u && totN <= CAP);
    u64* listP = s_list[wave][0];
    u64* listN = s_list[wave][1];

    // ---- pass 2: compact u64 keys (value-bits || 2047-idx) to LDS; rv dies here
#pragma unroll
    for (int q = 0; q < 8; ++q) {
#pragma unroll
        for (int c = 0; c < 4; ++c) {
            float v = rv[q*4+c];
            u32 fi = (u32)(q * 256 + lane * 4 + c);
            if (fastP && v > TH)
                listP[offP++] = ((u64)__float_as_uint(v)  << 32) | (u64)(2047u - fi);
            if (fastN && v < -TH)
                listN[offN++] = ((u64)__float_as_uint(-v) << 32) | (u64)(2047u - fi);
        }
    }

    // ---- load lists to regs (4 u64 slots/lane per side)
    u64 p0 = 0, p1 = 0, p2 = 0, p3 = 0, n0 = 0, n1 = 0, n2 = 0, n3 = 0;
    if (fastP) {
        p0 = (lane       < (int)totP) ? listP[lane]       : 0ull;
        p1 = (lane + 64  < (int)totP) ? listP[lane + 64]  : 0ull;
        p2 = (lane + 128 < (int)totP) ? listP[lane + 128] : 0ull;
        p3 = (lane + 192 < (int)totP) ? listP[lane + 192] : 0ull;
    }
    if (fastN) {
        n0 = (lane       < (int)totN) ? listN[lane]       : 0ull;
        n1 = (lane + 64  < (int)totN) ? listN[lane + 64]  : 0ull;
        n2 = (lane + 128 < (int)totN) ? listN[lane + 128] : 0ull;
        n3 = (lane + 192 < (int)totN) ? listN[lane + 192] : 0ull;
    }

    // ---- fused dual bisect: P and N searches interleaved for 2x ILP on the
    // ballot->popc->SALU chain. Invariants per side: count(>=lo) > 32 or
    // lo is final; count(>=hi) < 32; keys distinct => exact at termination.
    u64 loP = ((u64)TH_BITS) << 32, hiP = 0xFFFFFFFF00000000ull;
    u64 loN = loP,                  hiN = hiP;
    bool aP = fastP, aN = fastN;

    // seed round 1 (both sides at SEED_LO)
    if (aP || aN) {
        int c1P = aP ? cnt4(p0, p1, p2, p3, SEED_LO) : 0;
        int c1N = aN ? cnt4(n0, n1, n2, n3, SEED_LO) : 0;
        if (aP) { if (c1P == 32) { loP = SEED_LO; aP = false; }
                  else if (c1P > 32) loP = SEED_LO; else hiP = SEED_LO; }
        if (aN) { if (c1N == 32) { loN = SEED_LO; aN = false; }
                  else if (c1N > 32) loN = SEED_LO; else hiN = SEED_LO; }
    }
    // seed round 2 (only sides that cleared SEED_LO probe SEED_HI)
    {
        bool sP = aP && (loP == SEED_LO);
        bool sN = aN && (loN == SEED_LO);
        if (sP || sN) {
            int c2P = sP ? cnt4(p0, p1, p2, p3, SEED_HI) : 0;
            int c2N = sN ? cnt4(n0, n1, n2, n3, SEED_HI) : 0;
            if (sP) { if (c2P == 32) { loP = SEED_HI; aP = false; }
                      else if (c2P > 32) loP = SEED_HI; else hiP = SEED_HI; }
            if (sN) { if (c2N == 32) { loN = SEED_HI; aN = false; }
                      else if (c2N > 32) loN = SEED_HI; else hiN = SEED_HI; }
        }
    }
    while (aP || aN) {
        u64 midP = loP + ((hiP - loP) >> 1);
        u64 midN = loN + ((hiN - loN) >> 1);
        int cmP = aP ? cnt4(p0, p1, p2, p3, midP) : 0;
        int cmN = aN ? cnt4(n0, n1, n2, n3, midN) : 0;
        if (aP) {
            if (cmP >= 32) { loP = midP; if (cmP == 32) aP = false; }
            else hiP = midP;
            if (hiP - loP <= 1ull) aP = false;
        }
        if (aN) {
            if (cmN >= 32) { loN = midN; if (cmN == 32) aN = false; }
            else hiN = midN;
            if (hiN - loN <= 1ull) aN = false;
        }
    }
    const u64 cutP = loP, cutN = loN;

    // ---- energy terms
    float PtmpP = 0.f, NtmpN = 0.f;
    if (fastP) {
        float ts = (p0 >= cutP ? valof(p0) : 0.f) + (p1 >= cutP ? valof(p1) : 0.f)
                 + (p2 >= cutP ? valof(p2) : 0.f) + (p3 >= cutP ? valof(p3) : 0.f);
        ts = wsum_f(ts);
        PtmpP = FACTOR * (sumP - ts);
    }
    if (fastN) {
        float ts = (n0 >= cutN ? valof(n0) : 0.f) + (n1 >= cutN ? valof(n1) : 0.f)
                 + (n2 >= cutN ? valof(n2) : 0.f) + (n3 >= cutN ? valof(n3) : 0.f);
        ts = wsum_f(ts);
        NtmpN = FACTOR * (sumN - ts);
    }

    // ---- zeros + scatter back-to-back: lines stay L2-resident between the
    // zero store and the winner store -> single write-back, no RMW.
#pragma unroll
    for (int q = 0; q < 8; ++q)
        out4[q * 64 + lane] = make_float4(0.f, 0.f, 0.f, 0.f);

    asm volatile("s_waitcnt vmcnt(0)" ::: "memory");

    const bool anyslow = !(fastP && fastN);
    if (fastP) {
#pragma unroll
        for (int sl = 0; sl < 4; ++sl) {
            u64 k = (sl == 0) ? p0 : (sl == 1) ? p1 : (sl == 2) ? p2 : p3;
            if (k >= cutP) {
                int idx = 2047 - (int)(k & 0x7FFull);
                float val = valof(k) + PtmpP;
                if (anyslow) atomicAdd(&outrow[idx], val);
                else         outrow[idx] = val;
            }
        }
    }
    if (fastN) {
#pragma unroll
        for (int sl = 0; sl < 4; ++sl) {
            u64 k = (sl == 0) ? n0 : (sl == 1) ? n1 : (sl == 2) ? n2 : n3;
            if (k >= cutN) {
                int idx = 2047 - (int)(k & 0x7FFull);
                float val = -(valof(k) + NtmpN);
                if (anyslow) atomicAdd(&outrow[idx], val);
                else         outrow[idx] = val;
            }
        }
    }
    if (!fastP) slow_side(xr, outrow, lane, 0, sumP);
    if (!fastN) slow_side(xr, outrow, lane, 1, sumN);
}

extern "C" void kernel_launch(void* const* d_in, const int* in_sizes, int n_in,
                              void* d_out, int out_size, void* d_ws, size_t ws_size,
                              hipStream_t stream) {
    const float* x = (const float*)d_in[0];
    float* out = (float*)d_out;
    const int rows = in_sizes[0] / D;          // 16384
    kcomp_kernel<<<rows / WPB, TPB, 0, stream>>>(x, out);
}

// Round 9
// 50.381 us; speedup vs baseline: 1.1477x; 1.1477x over previous
//
#include <hip/hip_runtime.h>
#include <stdint.h>

typedef unsigned int u32;
typedef unsigned long long u64;

#define FACTOR  6.26f
#define D       2048
#define TPB     256
#define WPB     4        // one row per wave
#define CAP     256      // per-side candidate list capacity (mean 137, sd 11.3)
#define TH      1.5f
#define TH_BITS 0x3FC00000u

// Seeds (float bits) for the 32nd-largest of 2048 N(0,1): 2.15 +/- 0.07.
#define SEEDF_LO 0x3FE66666u   // 1.80f
#define SEEDF_HI 0x402147AEu   // 2.52f

__device__ __forceinline__ float wsum_f(float v) {
#pragma unroll
    for (int d = 1; d < 64; d <<= 1) v += __shfl_xor(v, d, 64);
    return v;
}
__device__ __forceinline__ u32 wsum_u(u32 v) {
#pragma unroll
    for (int d = 1; d < 64; d <<= 1) v += __shfl_xor(v, d, 64);
    return v;
}

__device__ __forceinline__ int cnt4f(u32 a, u32 b, u32 c, u32 d, u32 m) {
    return __popcll(__ballot(a >= m)) + __popcll(__ballot(b >= m))
         + __popcll(__ballot(c >= m)) + __popcll(__ballot(d >= m));
}

struct Cut32 { u32 bF; u32 idxCut; };
// winner(elem) <=> kf > bF || (kf == bF && (2047-idx) >= idxCut)

// Exact cut over the compacted list (float-bits bisect + secant, index
// resolution only on float-value ties). Preconditions: tot in [32,CAP],
// real keys have kf > TH_BITS, empty slots kf==0, indices distinct.
__device__ __forceinline__ Cut32 find_cut32(u32 kf0, u32 kf1, u32 kf2, u32 kf3,
                                            u64 k0, u64 k1, u64 k2, u64 k3,
                                            int tot) {
    u32 bLo = TH_BITS;     int cLo = tot;   // count(>=bLo) = tot >= 32
    u32 bHi = 0x7F800001u; int cHi = 0;     // count(>=bHi) = 0
    {
        int c = cnt4f(kf0, kf1, kf2, kf3, SEEDF_LO);
        if (c == 32) { Cut32 r; r.bF = SEEDF_LO; r.idxCut = 0u; return r; }
        if (c > 32) {
            bLo = SEEDF_LO; cLo = c;
            int c2 = cnt4f(kf0, kf1, kf2, kf3, SEEDF_HI);
            if (c2 == 32) { Cut32 r; r.bF = SEEDF_HI; r.idxCut = 0u; return r; }
            if (c2 > 32) { bLo = SEEDF_HI; cLo = c2; } else { bHi = SEEDF_HI; cHi = c2; }
        } else { bHi = SEEDF_LO; cHi = c; }
    }
    int it = 0;
    while (bHi - bLo > 1u) {
        u32 bmid;
        if (it & 1) {
            bmid = bLo + ((bHi - bLo) >> 1);             // guaranteed progress
        } else {                                          // secant in float space
            float fLo = __uint_as_float(bLo), fHi = __uint_as_float(bHi);
            float tt = (float)(cLo - 32) / (float)(cLo - cHi);
            u32 bs = __float_as_uint(fLo + tt * (fHi - fLo));
            bmid = (bs <= bLo) ? (bLo + 1u) : ((bs >= bHi) ? (bHi - 1u) : bs);
        }
        int c = cnt4f(kf0, kf1, kf2, kf3, bmid);
        if (c == 32) { Cut32 r; r.bF = bmid; r.idxCut = 0u; return r; }
        if (c > 32) { bLo = bmid; cLo = c; } else { bHi = bmid; cHi = c; }
        ++it;
    }
    // Rare: duplicates of float value bLo straddle the cut.
    // cHi == count(kf >= bLo+1) (bHi == bLo+1 here); fill = 32 - cHi >= 1.
    int fill = 32 - cHi;
    u32 il0 = (u32)(k0 & 0x7FFull), il1 = (u32)(k1 & 0x7FFull),
        il2 = (u32)(k2 & 0x7FFull), il3 = (u32)(k3 & 0x7FFull);
    u32 lo = 0u, hi = 2048u;
    while (hi - lo > 1u) {
        u32 m = (lo + hi) >> 1;
        int c = __popcll(__ballot(kf0 == bLo && il0 >= m))
              + __popcll(__ballot(kf1 == bLo && il1 >= m))
              + __popcll(__ballot(kf2 == bLo && il2 >= m))
              + __popcll(__ballot(kf3 == bLo && il3 >= m));
        if (c >= fill) { lo = m; if (c == fill) break; } else hi = m;
    }
    Cut32 r; r.bF = bLo; r.idxCut = lo;   // distinct indices => exactly fill ties chosen
    return r;
}

// Cold exact fallback (degenerate rows only): full-row u64-key bisect with
// global re-reads + atomicAdd scatter (handles P/N index overlap possible
// only here). Called AFTER zeros are stored and drained.
__device__ __attribute__((noinline))
void slow_side(const float4* __restrict__ xr, float* __restrict__ outrow,
               int lane, int neg, float sum) {
    u64 lo = 0ull, hi = ((u64)0x7F800001u) << 32;
    while (hi - lo > 1ull) {
        u64 mid = lo + ((hi - lo) >> 1);
        u32 cl = 0;
#pragma unroll 1
        for (int q = 0; q < 8; ++q) {
            float4 f = xr[q * 64 + lane];
            float vv[4] = {f.x, f.y, f.z, f.w};
#pragma unroll
            for (int c = 0; c < 4; ++c) {
                float v = neg ? -vv[c] : vv[c];
                float pv = v > 0.f ? v : 0.f;
                int idx = q * 256 + lane * 4 + c;
                u64 k = ((u64)__float_as_uint(pv) << 32) | (u64)(u32)(2047 - idx);
                cl += (k >= mid) ? 1u : 0u;
            }
        }
        u32 c = wsum_u(cl);
        if (c >= 32u) { lo = mid; if (c == 32u) break; } else hi = mid;
    }
    float ts = 0.f;
#pragma unroll 1
    for (int q = 0; q < 8; ++q) {
        float4 f = xr[q * 64 + lane];
        float vv[4] = {f.x, f.y, f.z, f.w};
#pragma unroll
        for (int c = 0; c < 4; ++c) {
            float v = neg ? -vv[c] : vv[c];
            float pv = v > 0.f ? v : 0.f;
            int idx = q * 256 + lane * 4 + c;
            u64 k = ((u64)__float_as_uint(pv) << 32) | (u64)(u32)(2047 - idx);
            if (k >= lo) ts += pv;
        }
    }
    ts = wsum_f(ts);
    float tmp = FACTOR * (sum - ts);
    float sgn = neg ? -1.f : 1.f;
#pragma unroll 1
    for (int q = 0; q < 8; ++q) {
        float4 f = xr[q * 64 + lane];
        float vv[4] = {f.x, f.y, f.z, f.w};
#pragma unroll
        for (int c = 0; c < 4; ++c) {
            float v = neg ? -vv[c] : vv[c];
            float pv = v > 0.f ? v : 0.f;
            int idx = q * 256 + lane * 4 + c;
            u64 k = ((u64)__float_as_uint(pv) << 32) | (u64)(u32)(2047 - idx);
            if (k >= lo) atomicAdd(&outrow[idx], sgn * (pv + tmp));
        }
    }
}

__global__ void __launch_bounds__(TPB, 8)
kcomp_kernel(const float* __restrict__ x, float* __restrict__ out) {
    __shared__ u64 s_list[WPB][2][CAP];   // 16 KiB/block, per-wave private

    const int t    = threadIdx.x;
    const int lane = t & 63;
    const int wave = t >> 6;
    const size_t rbase = (size_t)(blockIdx.x * WPB + wave) * D;

    const float4* xr     = reinterpret_cast<const float4*>(x + rbase);
    float4*       out4   = reinterpret_cast<float4*>(out + rbase);
    float*        outrow = out + rbase;

    // ---- pass 1: load row; plain sum + abs-sum (abs = free VOP3 modifier)
    float rv[32];
    float s = 0.f, sa = 0.f;
    u32 cP = 0, cN = 0;
#pragma unroll
    for (int q = 0; q < 8; ++q) {
        float4 f = xr[q * 64 + lane];
        rv[q*4+0] = f.x; rv[q*4+1] = f.y; rv[q*4+2] = f.z; rv[q*4+3] = f.w;
#pragma unroll
        for (int c = 0; c < 4; ++c) {
            float v = rv[q*4+c];
            s  += v;
            sa += __builtin_fabsf(v);
            cP += v > TH  ? 1u : 0u;
            cN += v < -TH ? 1u : 0u;
        }
    }

    // ---- packed prefix scan for compaction offsets
    u32 packed = cP | (cN << 16);
    u32 inc = packed;
#pragma unroll
    for (int d = 1; d < 64; d <<= 1) {
        u32 n = __shfl_up(inc, (unsigned)d, 64);
        if (lane >= d) inc += n;
    }
    u32 tot  = __shfl(inc, 63, 64);
    u32 exc  = inc - packed;
    u32 totP = tot & 0xffffu, totN = tot >> 16;
    u32 offP = exc & 0xffffu, offN = exc >> 16;
    float sw  = wsum_f(s);
    float saw = wsum_f(sa);
    float sumP = 0.5f * (saw + sw);
    float sumN = 0.5f * (saw - sw);

    const bool fastP = (totP >= 32u && totP <= CAP);
    const bool fastN = (totN >= 32u && totN <= CAP);
    u64* listP = s_list[wave][0];
    u64* listN = s_list[wave][1];

    // ---- pass 2: compact u64 keys (abs-value bits || 2047-idx) to LDS.
    // P/N are mutually exclusive (TH>0) -> one predicated region. rv dies here.
#pragma unroll
    for (int q = 0; q < 8; ++q) {
#pragma unroll
        for (int c = 0; c < 4; ++c) {
            float v = rv[q*4+c];
            bool isP = (v > TH)  && fastP;
            bool isN = (v < -TH) && fastN;
            if (isP || isN) {
                u32 fi = (u32)(q * 256 + lane * 4 + c);
                u64 key = ((u64)__float_as_uint(__builtin_fabsf(v)) << 32)
                        | (u64)(2047u - fi);
                u64* lst = isP ? listP : listN;
                u32  off = isP ? offP  : offN;
                lst[off] = key;
                offP += isP ? 1u : 0u;
                offN += isN ? 1u : 0u;
            }
        }
    }

    // ---- load lists to regs; extract float-bits keys
    u64 p0 = 0, p1 = 0, p2 = 0, p3 = 0, n0 = 0, n1 = 0, n2 = 0, n3 = 0;
    if (fastP) {
        p0 = (lane       < (int)totP) ? listP[lane]       : 0ull;
        p1 = (lane + 64  < (int)totP) ? listP[lane + 64]  : 0ull;
        p2 = (lane + 128 < (int)totP) ? listP[lane + 128] : 0ull;
        p3 = (lane + 192 < (int)totP) ? listP[lane + 192] : 0ull;
    }
    if (fastN) {
        n0 = (lane       < (int)totN) ? listN[lane]       : 0ull;
        n1 = (lane + 64  < (int)totN) ? listN[lane + 64]  : 0ull;
        n2 = (lane + 128 < (int)totN) ? listN[lane + 128] : 0ull;
        n3 = (lane + 192 < (int)totN) ? listN[lane + 192] : 0ull;
    }
    u32 pf0 = (u32)(p0 >> 32), pf1 = (u32)(p1 >> 32),
        pf2 = (u32)(p2 >> 32), pf3 = (u32)(p3 >> 32);
    u32 nf0 = (u32)(n0 >> 32), nf1 = (u32)(n1 >> 32),
        nf2 = (u32)(n2 >> 32), nf3 = (u32)(n3 >> 32);

    // ---- selection + energy terms (sequential per side; R8's fusion regressed)
    Cut32 cutP; cutP.bF = 0u; cutP.idxCut = 0u;
    Cut32 cutN; cutN.bF = 0u; cutN.idxCut = 0u;
    float PtmpP = 0.f, NtmpN = 0.f;
    if (fastP) {
        cutP = find_cut32(pf0, pf1, pf2, pf3, p0, p1, p2, p3, (int)totP);
        float ts = 0.f;
        if (pf0 > cutP.bF || (pf0 == cutP.bF && (u32)(p0 & 0x7FFull) >= cutP.idxCut)) ts += __uint_as_float(pf0);
        if (pf1 > cutP.bF || (pf1 == cutP.bF && (u32)(p1 & 0x7FFull) >= cutP.idxCut)) ts += __uint_as_float(pf1);
        if (pf2 > cutP.bF || (pf2 == cutP.bF && (u32)(p2 & 0x7FFull) >= cutP.idxCut)) ts += __uint_as_float(pf2);
        if (pf3 > cutP.bF || (pf3 == cutP.bF && (u32)(p3 & 0x7FFull) >= cutP.idxCut)) ts += __uint_as_float(pf3);
        ts = wsum_f(ts);
        PtmpP = FACTOR * (sumP - ts);
    }
    if (fastN) {
        cutN = find_cut32(nf0, nf1, nf2, nf3, n0, n1, n2, n3, (int)totN);
        float ts = 0.f;
        if (nf0 > cutN.bF || (nf0 == cutN.bF && (u32)(n0 & 0x7FFull) >= cutN.idxCut)) ts += __uint_as_float(nf0);
        if (nf1 > cutN.bF || (nf1 == cutN.bF && (u32)(n1 & 0x7FFull) >= cutN.idxCut)) ts += __uint_as_float(nf1);
        if (nf2 > cutN.bF || (nf2 == cutN.bF && (u32)(n2 & 0x7FFull) >= cutN.idxCut)) ts += __uint_as_float(nf2);
        if (nf3 > cutN.bF || (nf3 == cutN.bF && (u32)(n3 & 0x7FFull) >= cutN.idxCut)) ts += __uint_as_float(nf3);
        ts = wsum_f(ts);
        NtmpN = FACTOR * (sumN - ts);
    }

    // ---- zeros + scatter back-to-back: lines stay L2-resident -> single
    // write-back, no RMW (Round 7 mechanism, confirmed).
#pragma unroll
    for (int q = 0; q < 8; ++q)
        out4[q * 64 + lane] = make_float4(0.f, 0.f, 0.f, 0.f);

    asm volatile("s_waitcnt vmcnt(0)" ::: "memory");

    const bool anyslow = !(fastP && fastN);
    if (fastP) {
#pragma unroll
        for (int sl = 0; sl < 4; ++sl) {
            u64 k  = (sl == 0) ? p0  : (sl == 1) ? p1  : (sl == 2) ? p2  : p3;
            u32 kf = (sl == 0) ? pf0 : (sl == 1) ? pf1 : (sl == 2) ? pf2 : pf3;
            u32 il = (u32)(k & 0x7FFull);
            if (kf > cutP.bF || (kf == cutP.bF && il >= cutP.idxCut)) {
                int idx = 2047 - (int)il;
                float val = __uint_as_float(kf) + PtmpP;
                if (anyslow) atomicAdd(&outrow[idx], val);
                else         outrow[idx] = val;
            }
        }
    }
    if (fastN) {
#pragma unroll
        for (int sl = 0; sl < 4; ++sl) {
            u64 k  = (sl == 0) ? n0  : (sl == 1) ? n1  : (sl == 2) ? n2  : n3;
            u32 kf = (sl == 0) ? nf0 : (sl == 1) ? nf1 : (sl == 2) ? nf2 : nf3;
            u32 il = (u32)(k & 0x7FFull);
            if (kf > cutN.bF || (kf == cutN.bF && il >= cutN.idxCut)) {
                int idx = 2047 - (int)il;
                float val = -(__uint_as_float(kf) + NtmpN);
                if (anyslow) atomicAdd(&outrow[idx], val);
                else         outrow[idx] = val;
            }
        }
    }
    if (!fastP) slow_side(xr, outrow, lane, 0, sumP);
    if (!fastN) slow_side(xr, outrow, lane, 1, sumN);
}

extern "C" void kernel_launch(void* const* d_in, const int* in_sizes, int n_in,
                              void* d_out, int out_size, void* d_ws, size_t ws_size,
                              hipStream_t stream) {
    const float* x = (const float*)d_in[0];
    float* out = (float*)d_out;
    const int rows = in_sizes[0] / D;          // 16384
    kcomp_kernel<<<rows / WPB, TPB, 0, stream>>>(x, out);
}

// Round 10
// 50.108 us; speedup vs baseline: 1.1540x; 1.0054x over previous
//
#include <hip/hip_runtime.h>
#include <stdint.h>

typedef unsigned int u32;
typedef unsigned long long u64;

#define FACTOR  6.26f
#define D       2048
#define TPB     256
#define WPB     4        // one row per wave
#define CAP     256      // per-side candidate list capacity (mean 137, sd 11.3)
#define TH      1.5f
#define TH_BITS 0x3FC00000u

// Seeds (float bits) for the 32nd-largest of 2048 N(0,1): 2.15 +/- 0.07.
#define SEEDF_LO 0x3FE66666u   // 1.80f
#define SEEDF_HI 0x402147AEu   // 2.52f

__device__ __forceinline__ float wsum_f(float v) {
#pragma unroll
    for (int d = 1; d < 64; d <<= 1) v += __shfl_xor(v, d, 64);
    return v;
}
__device__ __forceinline__ u32 wsum_u(u32 v) {
#pragma unroll
    for (int d = 1; d < 64; d <<= 1) v += __shfl_xor(v, d, 64);
    return v;
}

__device__ __forceinline__ int cnt4f(u32 a, u32 b, u32 c, u32 d, u32 m) {
    return __popcll(__ballot(a >= m)) + __popcll(__ballot(b >= m))
         + __popcll(__ballot(c >= m)) + __popcll(__ballot(d >= m));
}

struct Cut32 { u32 bF; u32 idxCut; };
// winner(elem) <=> kf > bF || (kf == bF && (2047-idx) >= idxCut)

// Exact cut over the compacted list (float-bits bisect + secant, index
// resolution only on float-value ties). Preconditions: tot in [32,CAP],
// real keys have kf > TH_BITS, empty slots kf==0, indices distinct.
__device__ __forceinline__ Cut32 find_cut32(u32 kf0, u32 kf1, u32 kf2, u32 kf3,
                                            u64 k0, u64 k1, u64 k2, u64 k3,
                                            int tot) {
    u32 bLo = TH_BITS;     int cLo = tot;   // count(>=bLo) = tot >= 32
    u32 bHi = 0x7F800001u; int cHi = 0;     // count(>=bHi) = 0
    {
        int c = cnt4f(kf0, kf1, kf2, kf3, SEEDF_LO);
        if (c == 32) { Cut32 r; r.bF = SEEDF_LO; r.idxCut = 0u; return r; }
        if (c > 32) {
            bLo = SEEDF_LO; cLo = c;
            int c2 = cnt4f(kf0, kf1, kf2, kf3, SEEDF_HI);
            if (c2 == 32) { Cut32 r; r.bF = SEEDF_HI; r.idxCut = 0u; return r; }
            if (c2 > 32) { bLo = SEEDF_HI; cLo = c2; } else { bHi = SEEDF_HI; cHi = c2; }
        } else { bHi = SEEDF_LO; cHi = c; }
    }
    int it = 0;
    while (bHi - bLo > 1u) {
        u32 bmid;
        if (it & 1) {
            bmid = bLo + ((bHi - bLo) >> 1);             // guaranteed progress
        } else {                                          // secant in float space
            float fLo = __uint_as_float(bLo), fHi = __uint_as_float(bHi);
            float tt = (float)(cLo - 32) / (float)(cLo - cHi);
            u32 bs = __float_as_uint(fLo + tt * (fHi - fLo));
            bmid = (bs <= bLo) ? (bLo + 1u) : ((bs >= bHi) ? (bHi - 1u) : bs);
        }
        int c = cnt4f(kf0, kf1, kf2, kf3, bmid);
        if (c == 32) { Cut32 r; r.bF = bmid; r.idxCut = 0u; return r; }
        if (c > 32) { bLo = bmid; cLo = c; } else { bHi = bmid; cHi = c; }
        ++it;
    }
    // Rare: duplicates of float value bLo straddle the cut.
    // cHi == count(kf >= bLo+1); fill = 32 - cHi >= 1.
    int fill = 32 - cHi;
    u32 il0 = (u32)(k0 & 0x7FFull), il1 = (u32)(k1 & 0x7FFull),
        il2 = (u32)(k2 & 0x7FFull), il3 = (u32)(k3 & 0x7FFull);
    u32 lo = 0u, hi = 2048u;
    while (hi - lo > 1u) {
        u32 m = (lo + hi) >> 1;
        int c = __popcll(__ballot(kf0 == bLo && il0 >= m))
              + __popcll(__ballot(kf1 == bLo && il1 >= m))
              + __popcll(__ballot(kf2 == bLo && il2 >= m))
              + __popcll(__ballot(kf3 == bLo && il3 >= m));
        if (c >= fill) { lo = m; if (c == fill) break; } else hi = m;
    }
    Cut32 r; r.bF = bLo; r.idxCut = lo;   // distinct indices => exactly fill ties chosen
    return r;
}

// Cold exact fallback (degenerate rows only): full-row u64-key bisect with
// global re-reads + atomicAdd scatter (handles P/N index overlap possible
// only here). Called AFTER zeros are stored and drained.
__device__ __attribute__((noinline))
void slow_side(const float4* __restrict__ xr, float* __restrict__ outrow,
               int lane, int neg, float sum) {
    u64 lo = 0ull, hi = ((u64)0x7F800001u) << 32;
    while (hi - lo > 1ull) {
        u64 mid = lo + ((hi - lo) >> 1);
        u32 cl = 0;
#pragma unroll 1
        for (int q = 0; q < 8; ++q) {
            float4 f = xr[q * 64 + lane];
            float vv[4] = {f.x, f.y, f.z, f.w};
#pragma unroll
            for (int c = 0; c < 4; ++c) {
                float v = neg ? -vv[c] : vv[c];
                float pv = v > 0.f ? v : 0.f;
                int idx = q * 256 + lane * 4 + c;
                u64 k = ((u64)__float_as_uint(pv) << 32) | (u64)(u32)(2047 - idx);
                cl += (k >= mid) ? 1u : 0u;
            }
        }
        u32 c = wsum_u(cl);
        if (c >= 32u) { lo = mid; if (c == 32u) break; } else hi = mid;
    }
    float ts = 0.f;
#pragma unroll 1
    for (int q = 0; q < 8; ++q) {
        float4 f = xr[q * 64 + lane];
        float vv[4] = {f.x, f.y, f.z, f.w};
#pragma unroll
        for (int c = 0; c < 4; ++c) {
            float v = neg ? -vv[c] : vv[c];
            float pv = v > 0.f ? v : 0.f;
            int idx = q * 256 + lane * 4 + c;
            u64 k = ((u64)__float_as_uint(pv) << 32) | (u64)(u32)(2047 - idx);
            if (k >= lo) ts += pv;
        }
    }
    ts = wsum_f(ts);
    float tmp = FACTOR * (sum - ts);
    float sgn = neg ? -1.f : 1.f;
#pragma unroll 1
    for (int q = 0; q < 8; ++q) {
        float4 f = xr[q * 64 + lane];
        float vv[4] = {f.x, f.y, f.z, f.w};
#pragma unroll
        for (int c = 0; c < 4; ++c) {
            float v = neg ? -vv[c] : vv[c];
            float pv = v > 0.f ? v : 0.f;
            int idx = q * 256 + lane * 4 + c;
            u64 k = ((u64)__float_as_uint(pv) << 32) | (u64)(u32)(2047 - idx);
            if (k >= lo) atomicAdd(&outrow[idx], sgn * (pv + tmp));
        }
    }
}

__global__ void __launch_bounds__(TPB, 8)
kcomp_kernel(const float* __restrict__ x, float* __restrict__ out) {
    __shared__ u64 s_list[WPB][2][CAP];   // 16 KiB/block, per-wave private

    const int t    = threadIdx.x;
    const int lane = t & 63;
    const int wave = t >> 6;
    const size_t rbase = (size_t)(blockIdx.x * WPB + wave) * D;

    const float4* xr     = reinterpret_cast<const float4*>(x + rbase);
    float4*       out4   = reinterpret_cast<float4*>(out + rbase);
    float*        outrow = out + rbase;

    // ---- pass 1: load row; plain sum + abs-sum (abs = free VOP3 modifier)
    float rv[32];
    float s = 0.f, sa = 0.f;
    u32 cP = 0, cN = 0;
#pragma unroll
    for (int q = 0; q < 8; ++q) {
        float4 f = xr[q * 64 + lane];
        rv[q*4+0] = f.x; rv[q*4+1] = f.y; rv[q*4+2] = f.z; rv[q*4+3] = f.w;
#pragma unroll
        for (int c = 0; c < 4; ++c) {
            float v = rv[q*4+c];
            s  += v;
            sa += __builtin_fabsf(v);
            cP += v > TH  ? 1u : 0u;
            cN += v < -TH ? 1u : 0u;
        }
    }

    // ---- packed prefix scan for compaction offsets
    u32 packed = cP | (cN << 16);
    u32 inc = packed;
#pragma unroll
    for (int d = 1; d < 64; d <<= 1) {
        u32 n = __shfl_up(inc, (unsigned)d, 64);
        if (lane >= d) inc += n;
    }
    u32 tot  = __shfl(inc, 63, 64);
    u32 exc  = inc - packed;
    u32 totP = tot & 0xffffu, totN = tot >> 16;
    u32 offP = exc & 0xffffu, offN = exc >> 16;
    float sw  = wsum_f(s);
    float saw = wsum_f(sa);
    float sumP = 0.5f * (saw + sw);
    float sumN = 0.5f * (saw - sw);

    const bool fastP = (totP >= 32u && totP <= CAP);
    const bool fastN = (totN >= 32u && totN <= CAP);
    u64* listP = s_list[wave][0];
    u64* listN = s_list[wave][1];

    // ---- pass 2: compact u64 keys (value-bits || 2047-idx) to LDS.
    // Two independent predicated regions (R7 form): merged P/N region (R9)
    // cost +2us via pointer-select VALU + doubled LDS write conflicts.
#pragma unroll
    for (int q = 0; q < 8; ++q) {
#pragma unroll
        for (int c = 0; c < 4; ++c) {
            float v = rv[q*4+c];
            u32 fi = (u32)(q * 256 + lane * 4 + c);
            if (fastP && v > TH)
                listP[offP++] = ((u64)__float_as_uint(v)  << 32) | (u64)(2047u - fi);
            if (fastN && v < -TH)
                listN[offN++] = ((u64)__float_as_uint(-v) << 32) | (u64)(2047u - fi);
        }
    }

    // ---- load lists to regs; extract float-bits keys
    u64 p0 = 0, p1 = 0, p2 = 0, p3 = 0, n0 = 0, n1 = 0, n2 = 0, n3 = 0;
    if (fastP) {
        p0 = (lane       < (int)totP) ? listP[lane]       : 0ull;
        p1 = (lane + 64  < (int)totP) ? listP[lane + 64]  : 0ull;
        p2 = (lane + 128 < (int)totP) ? listP[lane + 128] : 0ull;
        p3 = (lane + 192 < (int)totP) ? listP[lane + 192] : 0ull;
    }
    if (fastN) {
        n0 = (lane       < (int)totN) ? listN[lane]       : 0ull;
        n1 = (lane + 64  < (int)totN) ? listN[lane + 64]  : 0ull;
        n2 = (lane + 128 < (int)totN) ? listN[lane + 128] : 0ull;
        n3 = (lane + 192 < (int)totN) ? listN[lane + 192] : 0ull;
    }
    u32 pf0 = (u32)(p0 >> 32), pf1 = (u32)(p1 >> 32),
        pf2 = (u32)(p2 >> 32), pf3 = (u32)(p3 >> 32);
    u32 nf0 = (u32)(n0 >> 32), nf1 = (u32)(n1 >> 32),
        nf2 = (u32)(n2 >> 32), nf3 = (u32)(n3 >> 32);

    // ---- selection + energy terms (sequential per side; R8's fusion regressed)
    Cut32 cutP; cutP.bF = 0u; cutP.idxCut = 0u;
    Cut32 cutN; cutN.bF = 0u; cutN.idxCut = 0u;
    float PtmpP = 0.f, NtmpN = 0.f;
    if (fastP) {
        cutP = find_cut32(pf0, pf1, pf2, pf3, p0, p1, p2, p3, (int)totP);
        float ts = 0.f;
        if (pf0 > cutP.bF || (pf0 == cutP.bF && (u32)(p0 & 0x7FFull) >= cutP.idxCut)) ts += __uint_as_float(pf0);
        if (pf1 > cutP.bF || (pf1 == cutP.bF && (u32)(p1 & 0x7FFull) >= cutP.idxCut)) ts += __uint_as_float(pf1);
        if (pf2 > cutP.bF || (pf2 == cutP.bF && (u32)(p2 & 0x7FFull) >= cutP.idxCut)) ts += __uint_as_float(pf2);
        if (pf3 > cutP.bF || (pf3 == cutP.bF && (u32)(p3 & 0x7FFull) >= cutP.idxCut)) ts += __uint_as_float(pf3);
        ts = wsum_f(ts);
        PtmpP = FACTOR * (sumP - ts);
    }
    if (fastN) {
        cutN = find_cut32(nf0, nf1, nf2, nf3, n0, n1, n2, n3, (int)totN);
        float ts = 0.f;
        if (nf0 > cutN.bF || (nf0 == cutN.bF && (u32)(n0 & 0x7FFull) >= cutN.idxCut)) ts += __uint_as_float(nf0);
        if (nf1 > cutN.bF || (nf1 == cutN.bF && (u32)(n1 & 0x7FFull) >= cutN.idxCut)) ts += __uint_as_float(nf1);
        if (nf2 > cutN.bF || (nf2 == cutN.bF && (u32)(n2 & 0x7FFull) >= cutN.idxCut)) ts += __uint_as_float(nf2);
        if (nf3 > cutN.bF || (nf3 == cutN.bF && (u32)(n3 & 0x7FFull) >= cutN.idxCut)) ts += __uint_as_float(nf3);
        ts = wsum_f(ts);
        NtmpN = FACTOR * (sumN - ts);
    }

    // ---- zeros + scatter back-to-back: lines stay L2-resident -> single
    // write-back, no RMW (Round 7 mechanism, confirmed).
#pragma unroll
    for (int q = 0; q < 8; ++q)
        out4[q * 64 + lane] = make_float4(0.f, 0.f, 0.f, 0.f);

    asm volatile("s_waitcnt vmcnt(0)" ::: "memory");

    const bool anyslow = !(fastP && fastN);
    if (fastP) {
#pragma unroll
        for (int sl = 0; sl < 4; ++sl) {
            u64 k  = (sl == 0) ? p0  : (sl == 1) ? p1  : (sl == 2) ? p2  : p3;
            u32 kf = (sl == 0) ? pf0 : (sl == 1) ? pf1 : (sl == 2) ? pf2 : pf3;
            u32 il = (u32)(k & 0x7FFull);
            if (kf > cutP.bF || (kf == cutP.bF && il >= cutP.idxCut)) {
                int idx = 2047 - (int)il;
                float val = __uint_as_float(kf) + PtmpP;
                if (anyslow) atomicAdd(&outrow[idx], val);
                else         outrow[idx] = val;
            }
        }
    }
    if (fastN) {
#pragma unroll
        for (int sl = 0; sl < 4; ++sl) {
            u64 k  = (sl == 0) ? n0  : (sl == 1) ? n1  : (sl == 2) ? n2  : n3;
            u32 kf = (sl == 0) ? nf0 : (sl == 1) ? nf1 : (sl == 2) ? nf2 : nf3;
            u32 il = (u32)(k & 0x7FFull);
            if (kf > cutN.bF || (kf == cutN.bF && il >= cutN.idxCut)) {
                int idx = 2047 - (int)il;
                float val = -(__uint_as_float(kf) + NtmpN);
                if (anyslow) atomicAdd(&outrow[idx], val);
                else         outrow[idx] = val;
            }
        }
    }
    if (!fastP) slow_side(xr, outrow, lane, 0, sumP);
    if (!fastN) slow_side(xr, outrow, lane, 1, sumN);
}

extern "C" void kernel_launch(void* const* d_in, const int* in_sizes, int n_in,
                              void* d_out, int out_size, void* d_ws, size_t ws_size,
                              hipStream_t stream) {
    const float* x = (const float*)d_in[0];
    float* out = (float*)d_out;
    const int rows = in_sizes[0] / D;          // 16384
    kcomp_kernel<<<rows / WPB, TPB, 0, stream>>>(x, out);
}